// Round 11
// baseline (529.155 us; speedup 1.0000x reference)
//
#include <hip/hip_runtime.h>
#include <stdint.h>
#include <stddef.h>

#define MROWS 32768
#define HDIM  512
#define CH    16384
#define BM 128
#define BN 128
#define BK 64

typedef __attribute__((ext_vector_type(8))) _Float16 half8;
typedef __attribute__((ext_vector_type(4))) _Float16 half4v;
typedef __attribute__((ext_vector_type(4))) float    f32x4;

// global -> LDS direct (16B/lane). LDS dest = wave-uniform base + lane*16.
static __device__ __forceinline__ void gld_lds16(const void* g, void* l) {
    __builtin_amdgcn_global_load_lds(
        (__attribute__((address_space(1))) void*)(uintptr_t)g,
        (__attribute__((address_space(3))) void*)(uint32_t)(uintptr_t)l,
        16, 0, 0);
}

// ---------------- fp32 -> fp16 row-structured conversion (weights) ------------
struct CvtJob  { const float* src; _Float16* dst; int srcld4, dstld, rowlen4, rows; };
struct CvtJobs { CvtJob j[11]; };

__global__ __launch_bounds__(256)
void cvt_rows(CvtJobs J) {
    const CvtJob jb = J.j[blockIdx.y];
    const int row = blockIdx.x;
    if (row >= jb.rows) return;
    const float4* __restrict__ s = (const float4*)jb.src + (size_t)row * jb.srcld4;
    _Float16* __restrict__ d = jb.dst + (size_t)row * jb.dstld;
    for (int c = threadIdx.x; c < jb.rowlen4; c += 256) {
        const float4 v = s[c];
        half4v o = { (_Float16)v.x, (_Float16)v.y, (_Float16)v.z, (_Float16)v.w };
        *(half4v*)(d + c * 4) = o;
    }
}

// ---------------- fp32 X chunk -> packed fp16 strip [X0|X1|X2] (ld 1536) ------
__global__ __launch_bounds__(384)
void cvt_chunk3(const float* __restrict__ x0, const float* __restrict__ x1,
                const float* __restrict__ x2, _Float16* __restrict__ dst) {
    const int row = blockIdx.x;
    const int mod = threadIdx.x >> 7;      // 0..2 (wave-uniform)
    const int c   = threadIdx.x & 127;     // float4 index within row
    const float* s = (mod == 0) ? x0 : (mod == 1) ? x1 : x2;
    const float4 v = ((const float4*)(s + (size_t)row * 512))[c];
    half4v o = { (_Float16)v.x, (_Float16)v.y, (_Float16)v.z, (_Float16)v.w };
    *(half4v*)(dst + (size_t)row * 1536 + mod * 512 + c * 4) = o;
}

// ---------------- fp32 -> fp16 transpose (512x512): dst[k][i] = src[i][k] -----
struct TcvtArgs { const float* src[3]; _Float16* dst; };
__global__ __launch_bounds__(256)
void tcvt512(TcvtArgs a) {
    __shared__ float t[32][33];
    const int m = blockIdx.z;
    const float* __restrict__ src = a.src[m];
    _Float16* __restrict__ dst = a.dst + (size_t)m * HDIM * HDIM;
    const int bx = blockIdx.x * 32, by = blockIdx.y * 32;
    const int tx = threadIdx.x & 31, ty = threadIdx.x >> 5;  // ty 0..7
    #pragma unroll
    for (int q = 0; q < 4; ++q)
        t[ty + q * 8][tx] = src[(size_t)(by + ty + q * 8) * 512 + bx + tx];
    __syncthreads();
    #pragma unroll
    for (int q = 0; q < 4; ++q)
        dst[(size_t)(bx + ty + q * 8) * 512 + by + tx] = (_Float16)t[tx][ty + q * 8];
}

// ---------------- small matvec: y[m*512+i] = b[m][i] + sum_j W[m][i*ldw+woff+j]*x[m][j]
struct MvArgs { const float* W[3]; const float* x[3]; const float* b[3]; float* y; int ldw, woff; };
__global__ __launch_bounds__(256)
void mv3(MvArgs a) {
    const int m = blockIdx.y;
    const int i = blockIdx.x * 256 + threadIdx.x;
    const float* __restrict__ W = a.W[m] + (size_t)i * a.ldw + a.woff;
    const float* __restrict__ x = a.x[m];
    float s = a.b[m][i];
    for (int j = 0; j < 512; ++j) s += W[j] * x[j];
    a.y[m * 512 + i] = s;
}

// ---------------- GEMM: C = A @ W^T (+bias/epilogue), A fp16 via gld_lds ------
// Grid: x = M-block (fast-varying), y = N-block.
// EPI 0: fp16 store acc+bias.   1: fp16 store xsave * sigmoid(acc+bias)
//        (xsave = A-cols n0..n0+128 snapshotted from LDS; valid because the
//        gate multiplier matrix == the A matrix).
//     2: fp16 RMW C += acc.     3: fp32 store acc+bias (two-phase LDS).
// MODE 0: plain; blockIdx.z batches via zsA/zsW/zsC byte strides.
// MODE 1: y-split dual GEMM: y < ysplit -> config a; y >= ysplit -> config b
//         (independent GEMM, disjoint output columns; n0 remapped).
// MODE 2: y-split GEMM + cvt tail: y < ysplit -> GEMM a; y >= ysplit -> the
//         block converts 128 rows of fp32 X (cx0|cx1|cx2) into packed fp16
//         cdst (ld 1536) for the NEXT chunk — hides the cvt under the GEMM.
// OCC: EPI1 carries xsave -> 3 (spill-free, r8/r9-verified); others -> 4.
struct GemmP {
    const void* A1;
    const _Float16* W; const float* bias; void* C;
    int K, ldA1, ldw, ldc, coff;
    int zsA, zsW, zsC;   // MODE 0 per-blockIdx.z byte strides
    // MODE 1 second config:
    const void* A1b; const _Float16* Wb; const float* biasb;
    int Kb, ldwb, coffb, ysplit;
    // MODE 2 cvt tail:
    const float *cx0, *cx1, *cx2; _Float16* cdst;
};

template<int EPI, int OCC, int MODE>
__global__ __launch_bounds__(256, OCC)
void gemm_k(GemmP p) {
    __shared__ __align__(16) unsigned char smem[32768];
    _Float16* Asm = (_Float16*)smem;              // 128 x 64
    _Float16* Bsm = (_Float16*)(smem + 16384);    // 128 x 64

    const int tid  = threadIdx.x;

    if (MODE == 2 && blockIdx.y >= (unsigned)p.ysplit) {
        // cvt tail: this block converts 128 rows (3 x 128 float4 per row)
        const int r0 = blockIdx.x * 128;
        for (int j = tid; j < 128 * 384; j += 256) {
            const int r = j / 384;
            const int t = j - r * 384;
            const int m = t >> 7, c = t & 127;
            const float* s = (m == 0) ? p.cx0 : (m == 1 ? p.cx1 : p.cx2);
            const float4 v = ((const float4*)(s + (size_t)(r0 + r) * 512))[c];
            half4v o = { (_Float16)v.x, (_Float16)v.y, (_Float16)v.z, (_Float16)v.w };
            *(half4v*)(p.cdst + (size_t)(r0 + r) * 1536 + m * 512 + c * 4) = o;
        }
        return;
    }

    const int wid  = tid >> 6;
    const int lane = tid & 63;
    const int m0 = blockIdx.x * BM;

    const _Float16* __restrict__ A1h;
    const _Float16* __restrict__ Wp;
    const float* biasp;
    char* Cz;
    int K, ldA1, ldw, coff, n0;
    if (MODE == 1 && blockIdx.y >= (unsigned)p.ysplit) {
        A1h = (const _Float16*)p.A1b; Wp = p.Wb; biasp = p.biasb;
        Cz = (char*)p.C; K = p.Kb; ldA1 = p.ldA1; ldw = p.ldwb; coff = p.coffb;
        n0 = (blockIdx.y - p.ysplit) * BN;
    } else {
        const ptrdiff_t zz = (MODE == 0) ? (ptrdiff_t)blockIdx.z : 0;
        A1h = (const _Float16*)((const char*)p.A1 + zz * p.zsA);
        Wp  = (const _Float16*)((const char*)p.W + zz * p.zsW);
        biasp = p.bias;
        Cz = (char*)p.C + zz * p.zsC;
        K = p.K; ldA1 = p.ldA1; ldw = p.ldw; coff = p.coff;
        n0 = blockIdx.y * BN;
    }

    const int wr = (wid >> 1) * 64;
    const int wc = (wid & 1) * 64;
    const int l15 = lane & 15;
    const int lhi = lane >> 4;

    f32x4 acc[4][4] = {};
    half8 xsave[8];
    const int colsel = (tid & 15) * 8;        // this thread's epilogue col offset
    const int xtile  = n0 + (colsel & 64);    // k-tile holding those A columns
    const int xco    = colsel & 63;

    for (int kt = 0; kt < K; kt += BK) {
        #pragma unroll
        for (int i = 0; i < 4; ++i) {
            const int seg = wid * 256 + i * 64 + lane;  // 0..1023
            const int row = seg >> 3;                   // 0..127
            const int ke  = (seg & 7) * 8;              // 0..56
            gld_lds16(Wp  + (size_t)(n0 + row) * ldw  + kt + ke, &Bsm[seg * 8]);
            gld_lds16(A1h + (size_t)(m0 + row) * ldA1 + kt + ke, &Asm[seg * 8]);
        }
        __syncthreads();
        if (EPI == 1 && kt == xtile) {   // snapshot gate-multiplier from A tile
            #pragma unroll
            for (int q = 0; q < 8; ++q)
                xsave[q] = *(const half8*)&Asm[(q * 16 + (tid >> 4)) * BK + xco];
        }
        #pragma unroll
        for (int kk = 0; kk < BK; kk += 32) {
            half8 fa[4], fb[4];
            #pragma unroll
            for (int i = 0; i < 4; ++i) {
                fa[i] = *(const half8*)&Asm[(wr + i * 16 + l15) * BK + kk + lhi * 8];
                fb[i] = *(const half8*)&Bsm[(wc + i * 16 + l15) * BK + kk + lhi * 8];
            }
            #pragma unroll
            for (int i = 0; i < 4; ++i)
                #pragma unroll
                for (int j = 0; j < 4; ++j)
                    acc[i][j] = __builtin_amdgcn_mfma_f32_16x16x32_f16(fa[i], fb[j], acc[i][j], 0, 0, 0);
        }
        __syncthreads();
    }

    // D layout: col = lane&15, row = (lane>>4)*4 + reg  (verified m89/m91)
    if (EPI == 3) {
        float* Cf = (float*)smem;   // 64 x 128 fp32
        float* __restrict__ C = (float*)Cz;
        #pragma unroll
        for (int h = 0; h < 2; ++h) {
            if ((wr >> 6) == h) {
                #pragma unroll
                for (int j = 0; j < 4; ++j) {
                    const int col = wc + j * 16 + l15;
                    const float bia = biasp ? biasp[n0 + col] : 0.f;
                    #pragma unroll
                    for (int i = 0; i < 4; ++i)
                        #pragma unroll
                        for (int r = 0; r < 4; ++r)
                            Cf[(i * 16 + lhi * 4 + r) * 128 + col] = acc[i][j][r] + bia;
                }
            }
            __syncthreads();
            #pragma unroll
            for (int pph = 0; pph < 8; ++pph) {
                const int seg = pph * 256 + tid;    // 0..2047 float4
                const int row = seg >> 5, cs = seg & 31;
                const float4 v = *(const float4*)&Cf[row * 128 + cs * 4];
                *(float4*)&C[(size_t)(m0 + h * 64 + row) * p.ldc + n0 + cs * 4] = v;
            }
            __syncthreads();
        }
    } else {
        _Float16* Ct = (_Float16*)smem;   // 128 x 128 fp16
        #pragma unroll
        for (int j = 0; j < 4; ++j) {
            const int col = wc + j * 16 + l15;
            const float bia = (EPI == 2) ? 0.f : (biasp ? biasp[n0 + col] : 0.f);
            #pragma unroll
            for (int i = 0; i < 4; ++i)
                #pragma unroll
                for (int r = 0; r < 4; ++r) {
                    float v = acc[i][j][r] + bia;
                    if (EPI == 1) v = 1.f / (1.f + __expf(-v));   // store sigma
                    Ct[(wr + i * 16 + lhi * 4 + r) * 128 + col] = (_Float16)v;
                }
        }
        __syncthreads();
        _Float16* __restrict__ C = (_Float16*)Cz;
        #pragma unroll
        for (int pph = 0; pph < 8; ++pph) {
            const int seg = pph * 256 + tid;       // 0..2047 half8
            const int row = seg >> 4, cs = seg & 15;
            half8 hv = *(const half8*)&Ct[row * 128 + cs * 8];
            const size_t cidx = (size_t)(m0 + row) * p.ldc + coff + n0 + cs * 8;
            if (EPI == 1) hv = hv * xsave[pph];    // x * sigmoid, packed fp16
            if (EPI == 2) { const half8 old = *(const half8*)&C[cidx]; hv = hv + old; }
            *(half8*)&C[cidx] = hv;
        }
    }
}

// ---------------- LayerNorm(1024) + ReLU: d_out(h fp16) -> ws(h' fp16) --------
__global__ __launch_bounds__(256)
void ln_relu(const _Float16* __restrict__ hin, _Float16* __restrict__ hout,
             const float* __restrict__ gamma, const float* __restrict__ beta) {
    const int row  = blockIdx.x * 4 + (threadIdx.x >> 6);
    const int lane = threadIdx.x & 63;
    const _Float16* hr = hin + (size_t)row * 1024;
    _Float16* ho = hout + (size_t)row * 1024;
    const half8 v0 = *(const half8*)(hr + lane * 8);
    const half8 v1 = *(const half8*)(hr + 512 + lane * 8);
    float f0[8], f1[8];
    float s = 0.f, s2 = 0.f;
    #pragma unroll
    for (int j = 0; j < 8; ++j) {
        f0[j] = (float)v0[j]; s += f0[j]; s2 += f0[j] * f0[j];
        f1[j] = (float)v1[j]; s += f1[j]; s2 += f1[j] * f1[j];
    }
    #pragma unroll
    for (int off = 32; off > 0; off >>= 1) {
        s  += __shfl_xor(s,  off, 64);
        s2 += __shfl_xor(s2, off, 64);
    }
    const float mean = s * (1.f / 1024.f);
    const float var  = s2 * (1.f / 1024.f) - mean * mean;
    const float rstd = rsqrtf(var + 1e-5f);
    half8 o0, o1;
    #pragma unroll
    for (int j = 0; j < 8; ++j) {
        const int i0 = lane * 8 + j, i1 = 512 + lane * 8 + j;
        const float av = (f0[j] - mean) * rstd * gamma[i0] + beta[i0];
        const float bv = (f1[j] - mean) * rstd * gamma[i1] + beta[i1];
        o0[j] = (_Float16)(av > 0.f ? av : 0.f);
        o1[j] = (_Float16)(bv > 0.f ? bv : 0.f);
    }
    *(half8*)(ho + lane * 8) = o0;
    *(half8*)(ho + 512 + lane * 8) = o1;
}

// -----------------------------------------------------------------------------
extern "C" void kernel_launch(void* const* d_in, const int* in_sizes, int n_in,
                              void* d_out, int out_size, void* d_ws, size_t ws_size,
                              hipStream_t stream)
{
    (void)in_sizes; (void)n_in; (void)out_size;
    const size_t HH = (size_t)HDIM * HDIM;              // 262,144

    // ws layout (~113.8 MB; r9/r10 proved ws >= this):
    //   [0, 50.3MB)      slotB: gate/allf chunk (CH x 1536 fp16)
    //   [50.3, 100.7MB)  Xch: packed fp16 [X0|X1|X2] chunk (CH x 1536)
    //   [100.7MB, ...)   persistent fp16 weights + fp32 biases
    //   After the chunk loop, slotB+Xch are dead; h' (M x 1024 fp16, 67.1MB)
    //   reuses [0, 67.1MB) for the LN->fc2 handoff.
    _Float16* wsH   = (_Float16*)d_ws;
    _Float16* slotB = wsH;                               // CH*1536
    _Float16* Xch   = slotB + (size_t)CH * 1536;         // CH*1536
    _Float16* Wouth = Xch   + (size_t)CH * 1536;         // 3*HH
    _Float16* Wg2h  = Wouth + 3 * HH;                    // 3*HH
    _Float16* WvT   = Wg2h  + 3 * HH;                    // 3*HH
    _Float16* WcoT  = WvT   + 3 * HH;                    // 3*HH
    _Float16* Wbig  = WcoT  + 3 * HH;                    // 4*HH (1024 x 1024)
    _Float16* Wc2   = Wbig  + 4 * HH;                    // 1*HH (512 x 512)
    _Float16* fc1h  = Wc2   + 1 * HH;                    // 6*HH
    _Float16* fc2h  = fc1h  + 6 * HH;                    // 2*HH
    float*    bco   = (float*)(fc2h + 2 * HH);           // 3*512
    float*    beff  = bco + 3 * 512;                     // 3*512 (g0|g1|g2)
    _Float16* hws   = wsH;                               // h' after chunk loop
    const size_t need = (size_t)((char*)(beff + 3 * 512) - (char*)d_ws);
    if (ws_size < need) return;

    const float* X[3] = { (const float*)d_in[0], (const float*)d_in[1], (const float*)d_in[2] };
    const int asrc[3] = { 1, 0, 2 };   // gate m's attention-source modality

    // ---- weight prep (all tiny) ----
    CvtJobs cj;
    for (int m = 0; m < 3; ++m) {
        cj.j[m]     = { (const float*)d_in[5 + 4 * m], Wouth + m * HH, 128, 512, 128, 512 };
        cj.j[3 + m] = { (const float*)d_in[15 + 2 * m] + 512, Wg2h + m * HH, 256, 512, 128, 512 };
    }
    cj.j[6]  = { (const float*)d_in[15], Wbig,                    256, 1024, 128, 512 };
    cj.j[7]  = { (const float*)d_in[17], Wbig + 512 * 1024 + 512, 256, 1024, 128, 512 };
    cj.j[8]  = { (const float*)d_in[19], Wc2,                     256, 512,  128, 512 };
    cj.j[9]  = { (const float*)d_in[21], fc1h, 384, 1536, 384, 1024 };
    cj.j[10] = { (const float*)d_in[25], fc2h, 256, 1024, 256, 512 };
    cvt_rows<<<dim3(1024, 11, 1), 256, 0, stream>>>(cj);

    TcvtArgs ta;
    for (int m = 0; m < 3; ++m) ta.src[m] = (const float*)d_in[3 + 4 * m] + 2 * HH;
    ta.dst = WvT;
    tcvt512<<<dim3(16, 16, 3), 256, 0, stream>>>(ta);

    MvArgs mv;   // bco_a = bo_a + Wout_a @ bv_a
    for (int m = 0; m < 3; ++m) {
        mv.W[m] = (const float*)d_in[5 + 4 * m];
        mv.x[m] = (const float*)d_in[4 + 4 * m] + 2 * HDIM;
        mv.b[m] = (const float*)d_in[6 + 4 * m];
    }
    mv.y = bco; mv.ldw = 512; mv.woff = 0;
    mv3<<<dim3(2, 3, 1), 256, 0, stream>>>(mv);

    GemmP p;
    p.bias = nullptr; p.coff = 0;
    p.zsA = p.zsW = p.zsC = 0;
    p.A1b = nullptr; p.Wb = nullptr; p.biasb = nullptr;
    p.Kb = 0; p.ldwb = 0; p.coffb = 0; p.ysplit = 1 << 30;
    p.cx0 = p.cx1 = p.cx2 = nullptr; p.cdst = nullptr;

    // WcoT_a = WvT_a @ Wout_a^T  for a=0,1,2  (batched over z)
    p.A1 = WvT; p.ldA1 = 512;
    p.W = Wouth; p.ldw = 512;
    p.C = WcoT; p.ldc = 512;
    p.K = 512;
    p.zsA = (int)(HH * 2); p.zsW = (int)(HH * 2); p.zsC = (int)(HH * 2);
    gemm_k<0, 4, 0><<<dim3(4, 4, 3), 256, 0, stream>>>(p);

    // Wbig off-diagonal blocks, batched z=2:
    //   z0: Wbig[0:512, 512:1024]  = Wg2_0 @ Wco_1
    //   z1: Wbig[512:1024, 0:512]  = Wg2_1 @ Wco_0
    p.A1 = Wg2h; p.zsA = (int)(HH * 2);
    p.W = WcoT + HH; p.zsW = -(int)(HH * 2);
    p.C = Wbig + 512; p.ldc = 1024; p.zsC = (int)((512 * 1024 - 512) * 2);
    gemm_k<0, 4, 0><<<dim3(4, 4, 2), 256, 0, stream>>>(p);

    // Wc2 += Wg2_2 @ Wco_2  (RMW onto cvt'd Wg1_2)
    p.A1 = Wg2h + 2 * HH; p.zsA = 0;
    p.W = WcoT + 2 * HH; p.zsW = 0;
    p.C = Wc2; p.ldc = 512; p.zsC = 0;
    gemm_k<2, 4, 0><<<dim3(4, 4, 1), 256, 0, stream>>>(p);

    // beff_m = bg_m + Wg2_m @ bco_{asrc[m]}
    for (int m = 0; m < 3; ++m) {
        mv.W[m] = (const float*)d_in[15 + 2 * m];
        mv.x[m] = bco + asrc[m] * 512;
        mv.b[m] = (const float*)d_in[16 + 2 * m];
    }
    mv.y = beff; mv.ldw = 1024; mv.woff = 512;
    mv3<<<dim3(2, 3, 1), 256, 0, stream>>>(mv);

    // Xc(chunk0) = [X0 | X1 | X2], fp32 -> fp16 packed (ld 1536)
    cvt_chunk3<<<dim3(CH, 1, 1), 384, 0, stream>>>(X[0], X[1], X[2], Xch);

    // ---- main pipeline, 2 M-chunks; chunk1's cvt hides inside fc1(chunk0) ----
    _Float16* hbuf = (_Float16*)d_out;   // h: M x 1024 fp16 inside d_out
    for (int c = 0; c < 2; ++c) {
        const size_t roff = (size_t)c * CH;

        // Merged gate dispatch (y-split, all blocks useful):
        //   y<8 : slotB[:,0:1024]    = Xc01 * sigmoid(Xc01 @ Wbig^T + beff)
        //   y>=8: slotB[:,1024:1536] = Xc2  * sigmoid(Xc2  @ Wc2^T  + beff[1024:])
        p.A1 = Xch; p.ldA1 = 1536;
        p.W = Wbig; p.ldw = 1024;
        p.bias = beff;
        p.C = slotB; p.ldc = 1536; p.coff = 0;
        p.K = 1024;
        p.A1b = Xch + 1024; p.Wb = Wc2; p.biasb = beff + 1024;
        p.Kb = 512; p.ldwb = 512; p.coffb = 1024; p.ysplit = 8;
        gemm_k<1, 3, 1><<<dim3(CH / BM, 12, 1), 256, 0, stream>>>(p);

        // h_chunk = allf_chunk @ fc1^T + fc1_b -> d_out (fp16).
        // Chunk 0 additionally converts chunk 1's X into Xch via a y=8 tail
        // column (gate(c0) has consumed Xch; gate(c1) reads it next). No race.
        p.A1 = slotB; p.ldA1 = 1536;
        p.W = fc1h; p.ldw = 1536;
        p.bias = (const float*)d_in[22];
        p.C = hbuf + roff * 1024; p.ldc = 1024; p.coff = 0;
        p.K = 1536; p.ysplit = 8;
        if (c == 0) {
            p.cx0 = X[0] + (size_t)CH * HDIM;
            p.cx1 = X[1] + (size_t)CH * HDIM;
            p.cx2 = X[2] + (size_t)CH * HDIM;
            p.cdst = Xch;
            gemm_k<0, 4, 2><<<dim3(CH / BM, 9, 1), 256, 0, stream>>>(p);
        } else {
            gemm_k<0, 4, 0><<<dim3(CH / BM, 8, 1), 256, 0, stream>>>(p);
        }
    }

    // LayerNorm + ReLU: h (d_out) -> h' (ws; slotB/Xch region is dead now)
    ln_relu<<<dim3(MROWS / 4, 1, 1), 256, 0, stream>>>(
        hbuf, hws, (const float*)d_in[23], (const float*)d_in[24]);

    // out = h' @ fc2^T + fc2_b (fp32) directly into d_out, single dispatch.
    // h' lives in ws, so d_out is write-only here: no read/write hazard.
    p.A1 = hws; p.ldA1 = 1024;
    p.W = fc2h; p.ldw = 1024;
    p.bias = (const float*)d_in[26];
    p.C = d_out; p.ldc = HDIM; p.coff = 0;
    p.K = 1024; p.ysplit = 1 << 30;
    gemm_k<3, 4, 0><<<dim3(MROWS / BM, HDIM / BN, 1), 256, 0, stream>>>(p);
}

// Round 12
// 456.668 us; speedup vs baseline: 1.1587x; 1.1587x over previous
//
#include <hip/hip_runtime.h>
#include <stdint.h>
#include <stddef.h>

#define MROWS 32768
#define HDIM  512
#define CH    16384
#define BM 128
#define BN 128
#define BK 64

typedef __attribute__((ext_vector_type(8))) _Float16 half8;
typedef __attribute__((ext_vector_type(4))) _Float16 half4v;
typedef __attribute__((ext_vector_type(4))) float    f32x4;

// global -> LDS direct (16B/lane). LDS dest = wave-uniform base + lane*16.
static __device__ __forceinline__ void gld_lds16(const void* g, void* l) {
    __builtin_amdgcn_global_load_lds(
        (__attribute__((address_space(1))) void*)(uintptr_t)g,
        (__attribute__((address_space(3))) void*)(uint32_t)(uintptr_t)l,
        16, 0, 0);
}

// ---------------- fp32 -> fp16 row-structured conversion (weights) ------------
struct CvtJob  { const float* src; _Float16* dst; int srcld4, dstld, rowlen4, rows; };
struct CvtJobs { CvtJob j[11]; };

__global__ __launch_bounds__(256)
void cvt_rows(CvtJobs J) {
    const CvtJob jb = J.j[blockIdx.y];
    const int row = blockIdx.x;
    if (row >= jb.rows) return;
    const float4* __restrict__ s = (const float4*)jb.src + (size_t)row * jb.srcld4;
    _Float16* __restrict__ d = jb.dst + (size_t)row * jb.dstld;
    for (int c = threadIdx.x; c < jb.rowlen4; c += 256) {
        const float4 v = s[c];
        half4v o = { (_Float16)v.x, (_Float16)v.y, (_Float16)v.z, (_Float16)v.w };
        *(half4v*)(d + c * 4) = o;
    }
}

// ---------------- fp32 X chunk -> packed fp16 strip [X0|X1|X2] (ld 1536) ------
__global__ __launch_bounds__(384)
void cvt_chunk3(const float* __restrict__ x0, const float* __restrict__ x1,
                const float* __restrict__ x2, _Float16* __restrict__ dst) {
    const int row = blockIdx.x;
    const int mod = threadIdx.x >> 7;      // 0..2 (wave-uniform)
    const int c   = threadIdx.x & 127;     // float4 index within row
    const float* s = (mod == 0) ? x0 : (mod == 1) ? x1 : x2;
    const float4 v = ((const float4*)(s + (size_t)row * 512))[c];
    half4v o = { (_Float16)v.x, (_Float16)v.y, (_Float16)v.z, (_Float16)v.w };
    *(half4v*)(dst + (size_t)row * 1536 + mod * 512 + c * 4) = o;
}

// ---------------- fp32 -> fp16 transpose (512x512): dst[k][i] = src[i][k] -----
struct TcvtArgs { const float* src[3]; _Float16* dst; };
__global__ __launch_bounds__(256)
void tcvt512(TcvtArgs a) {
    __shared__ float t[32][33];
    const int m = blockIdx.z;
    const float* __restrict__ src = a.src[m];
    _Float16* __restrict__ dst = a.dst + (size_t)m * HDIM * HDIM;
    const int bx = blockIdx.x * 32, by = blockIdx.y * 32;
    const int tx = threadIdx.x & 31, ty = threadIdx.x >> 5;  // ty 0..7
    #pragma unroll
    for (int q = 0; q < 4; ++q)
        t[ty + q * 8][tx] = src[(size_t)(by + ty + q * 8) * 512 + bx + tx];
    __syncthreads();
    #pragma unroll
    for (int q = 0; q < 4; ++q)
        dst[(size_t)(bx + ty + q * 8) * 512 + by + tx] = (_Float16)t[tx][ty + q * 8];
}

// ---------------- small matvec: y[m*512+i] = b[m][i] + sum_j W[m][i*ldw+woff+j]*x[m][j]
struct MvArgs { const float* W[3]; const float* x[3]; const float* b[3]; float* y; int ldw, woff; };
__global__ __launch_bounds__(256)
void mv3(MvArgs a) {
    const int m = blockIdx.y;
    const int i = blockIdx.x * 256 + threadIdx.x;
    const float* __restrict__ W = a.W[m] + (size_t)i * a.ldw + a.woff;
    const float* __restrict__ x = a.x[m];
    float s = a.b[m][i];
    for (int j = 0; j < 512; ++j) s += W[j] * x[j];
    a.y[m * 512 + i] = s;
}

// ---------------- GEMM: C = A @ W^T (+bias/epilogue), A fp16 via gld_lds ------
// Grid: x = M-block (fast-varying), y = N-block.
// EPI 0: fp16 store acc+bias.
//     1: fp16 store Xmul * sigmoid(acc+bias); the multiplier IS the A-matrix
//        columns n0..n0+127 — reloaded coalesced from global in the epilogue
//        (L3-hit; replaces the r9-r11 xsave snapshot that cost 32 VGPRs and
//        forced OCC 3 on the gates).
//     2: fp16 RMW C += acc.     3: fp32 store acc+bias (two-phase LDS).
// MODE 0: plain; blockIdx.z batches via zsA/zsW/zsC byte strides.
// MODE 1: y-split dual GEMM: y < ysplit -> config a; y >= ysplit -> config b
//         (independent GEMM, disjoint output columns; n0 remapped).
// OCC: all instantiations spill-free at 4 now (xsave removed).
struct GemmP {
    const void* A1;
    const _Float16* W; const float* bias; void* C;
    int K, ldA1, ldw, ldc, coff;
    int zsA, zsW, zsC;   // MODE 0 per-blockIdx.z byte strides
    // MODE 1 second config:
    const void* A1b; const _Float16* Wb; const float* biasb;
    int Kb, ldwb, coffb, ysplit;
};

template<int EPI, int OCC, int MODE>
__global__ __launch_bounds__(256, OCC)
void gemm_k(GemmP p) {
    __shared__ __align__(16) unsigned char smem[32768];
    _Float16* Asm = (_Float16*)smem;              // 128 x 64
    _Float16* Bsm = (_Float16*)(smem + 16384);    // 128 x 64

    const int tid  = threadIdx.x;
    const int wid  = tid >> 6;
    const int lane = tid & 63;
    const int m0 = blockIdx.x * BM;

    const _Float16* __restrict__ A1h;
    const _Float16* __restrict__ Wp;
    const float* biasp;
    char* Cz;
    int K, ldA1, ldw, coff, n0;
    if (MODE == 1 && blockIdx.y >= (unsigned)p.ysplit) {
        A1h = (const _Float16*)p.A1b; Wp = p.Wb; biasp = p.biasb;
        Cz = (char*)p.C; K = p.Kb; ldA1 = p.ldA1; ldw = p.ldwb; coff = p.coffb;
        n0 = (blockIdx.y - p.ysplit) * BN;
    } else {
        const ptrdiff_t zz = (MODE == 0) ? (ptrdiff_t)blockIdx.z : 0;
        A1h = (const _Float16*)((const char*)p.A1 + zz * p.zsA);
        Wp  = (const _Float16*)((const char*)p.W + zz * p.zsW);
        biasp = p.bias;
        Cz = (char*)p.C + zz * p.zsC;
        K = p.K; ldA1 = p.ldA1; ldw = p.ldw; coff = p.coff;
        n0 = blockIdx.y * BN;
    }

    const int wr = (wid >> 1) * 64;
    const int wc = (wid & 1) * 64;
    const int l15 = lane & 15;
    const int lhi = lane >> 4;

    f32x4 acc[4][4] = {};

    for (int kt = 0; kt < K; kt += BK) {
        #pragma unroll
        for (int i = 0; i < 4; ++i) {
            const int seg = wid * 256 + i * 64 + lane;  // 0..1023
            const int row = seg >> 3;                   // 0..127
            const int ke  = (seg & 7) * 8;              // 0..56
            gld_lds16(Wp  + (size_t)(n0 + row) * ldw  + kt + ke, &Bsm[seg * 8]);
            gld_lds16(A1h + (size_t)(m0 + row) * ldA1 + kt + ke, &Asm[seg * 8]);
        }
        __syncthreads();
        #pragma unroll
        for (int kk = 0; kk < BK; kk += 32) {
            half8 fa[4], fb[4];
            #pragma unroll
            for (int i = 0; i < 4; ++i) {
                fa[i] = *(const half8*)&Asm[(wr + i * 16 + l15) * BK + kk + lhi * 8];
                fb[i] = *(const half8*)&Bsm[(wc + i * 16 + l15) * BK + kk + lhi * 8];
            }
            #pragma unroll
            for (int i = 0; i < 4; ++i)
                #pragma unroll
                for (int j = 0; j < 4; ++j)
                    acc[i][j] = __builtin_amdgcn_mfma_f32_16x16x32_f16(fa[i], fb[j], acc[i][j], 0, 0, 0);
        }
        __syncthreads();
    }

    // D layout: col = lane&15, row = (lane>>4)*4 + reg  (verified m89/m91)
    if (EPI == 3) {
        float* Cf = (float*)smem;   // 64 x 128 fp32
        float* __restrict__ C = (float*)Cz;
        #pragma unroll
        for (int h = 0; h < 2; ++h) {
            if ((wr >> 6) == h) {
                #pragma unroll
                for (int j = 0; j < 4; ++j) {
                    const int col = wc + j * 16 + l15;
                    const float bia = biasp ? biasp[n0 + col] : 0.f;
                    #pragma unroll
                    for (int i = 0; i < 4; ++i)
                        #pragma unroll
                        for (int r = 0; r < 4; ++r)
                            Cf[(i * 16 + lhi * 4 + r) * 128 + col] = acc[i][j][r] + bia;
                }
            }
            __syncthreads();
            #pragma unroll
            for (int pph = 0; pph < 8; ++pph) {
                const int seg = pph * 256 + tid;    // 0..2047 float4
                const int row = seg >> 5, cs = seg & 31;
                const float4 v = *(const float4*)&Cf[row * 128 + cs * 4];
                *(float4*)&C[(size_t)(m0 + h * 64 + row) * p.ldc + n0 + cs * 4] = v;
            }
            __syncthreads();
        }
    } else {
        _Float16* Ct = (_Float16*)smem;   // 128 x 128 fp16
        #pragma unroll
        for (int j = 0; j < 4; ++j) {
            const int col = wc + j * 16 + l15;
            const float bia = (EPI == 2) ? 0.f : (biasp ? biasp[n0 + col] : 0.f);
            #pragma unroll
            for (int i = 0; i < 4; ++i)
                #pragma unroll
                for (int r = 0; r < 4; ++r) {
                    float v = acc[i][j][r] + bia;
                    if (EPI == 1) v = 1.f / (1.f + __expf(-v));   // store sigma
                    Ct[(wr + i * 16 + lhi * 4 + r) * 128 + col] = (_Float16)v;
                }
        }
        __syncthreads();
        _Float16* __restrict__ C = (_Float16*)Cz;
        #pragma unroll
        for (int pph = 0; pph < 8; ++pph) {
            const int seg = pph * 256 + tid;       // 0..2047 half8
            const int row = seg >> 4, cs = seg & 15;
            half8 hv = *(const half8*)&Ct[row * 128 + cs * 8];
            const size_t cidx = (size_t)(m0 + row) * p.ldc + coff + n0 + cs * 8;
            if (EPI == 1) {
                // multiplier = A-matrix columns n0.. (gate: x * sigma), L3-hit
                const half8 xv = *(const half8*)(A1h + (size_t)(m0 + row) * ldA1
                                                 + n0 + cs * 8);
                hv = hv * xv;
            }
            if (EPI == 2) { const half8 old = *(const half8*)&C[cidx]; hv = hv + old; }
            *(half8*)&C[cidx] = hv;
        }
    }
}

// ---------------- LayerNorm(1024) + ReLU: d_out(h fp16) -> ws(h' fp16) --------
__global__ __launch_bounds__(256)
void ln_relu(const _Float16* __restrict__ hin, _Float16* __restrict__ hout,
             const float* __restrict__ gamma, const float* __restrict__ beta) {
    const int row  = blockIdx.x * 4 + (threadIdx.x >> 6);
    const int lane = threadIdx.x & 63;
    const _Float16* hr = hin + (size_t)row * 1024;
    _Float16* ho = hout + (size_t)row * 1024;
    const half8 v0 = *(const half8*)(hr + lane * 8);
    const half8 v1 = *(const half8*)(hr + 512 + lane * 8);
    float f0[8], f1[8];
    float s = 0.f, s2 = 0.f;
    #pragma unroll
    for (int j = 0; j < 8; ++j) {
        f0[j] = (float)v0[j]; s += f0[j]; s2 += f0[j] * f0[j];
        f1[j] = (float)v1[j]; s += f1[j]; s2 += f1[j] * f1[j];
    }
    #pragma unroll
    for (int off = 32; off > 0; off >>= 1) {
        s  += __shfl_xor(s,  off, 64);
        s2 += __shfl_xor(s2, off, 64);
    }
    const float mean = s * (1.f / 1024.f);
    const float var  = s2 * (1.f / 1024.f) - mean * mean;
    const float rstd = rsqrtf(var + 1e-5f);
    half8 o0, o1;
    #pragma unroll
    for (int j = 0; j < 8; ++j) {
        const int i0 = lane * 8 + j, i1 = 512 + lane * 8 + j;
        const float av = (f0[j] - mean) * rstd * gamma[i0] + beta[i0];
        const float bv = (f1[j] - mean) * rstd * gamma[i1] + beta[i1];
        o0[j] = (_Float16)(av > 0.f ? av : 0.f);
        o1[j] = (_Float16)(bv > 0.f ? bv : 0.f);
    }
    *(half8*)(ho + lane * 8) = o0;
    *(half8*)(ho + 512 + lane * 8) = o1;
}

// -----------------------------------------------------------------------------
extern "C" void kernel_launch(void* const* d_in, const int* in_sizes, int n_in,
                              void* d_out, int out_size, void* d_ws, size_t ws_size,
                              hipStream_t stream)
{
    (void)in_sizes; (void)n_in; (void)out_size;
    const size_t HH = (size_t)HDIM * HDIM;              // 262,144

    // ws layout (~113.8 MB; r9/r10 proved ws >= this):
    //   [0, 50.3MB)      slotB: gate/allf chunk (CH x 1536 fp16)
    //   [50.3, 100.7MB)  Xch: packed fp16 [X0|X1|X2] chunk (CH x 1536)
    //   [100.7MB, ...)   persistent fp16 weights + fp32 biases
    //   After the chunk loop, slotB+Xch are dead; h' (M x 1024 fp16, 67.1MB)
    //   reuses [0, 67.1MB) for the LN->fc2 handoff.
    _Float16* wsH   = (_Float16*)d_ws;
    _Float16* slotB = wsH;                               // CH*1536
    _Float16* Xch   = slotB + (size_t)CH * 1536;         // CH*1536
    _Float16* Wouth = Xch   + (size_t)CH * 1536;         // 3*HH
    _Float16* Wg2h  = Wouth + 3 * HH;                    // 3*HH
    _Float16* WvT   = Wg2h  + 3 * HH;                    // 3*HH
    _Float16* WcoT  = WvT   + 3 * HH;                    // 3*HH
    _Float16* Wbig  = WcoT  + 3 * HH;                    // 4*HH (1024 x 1024)
    _Float16* Wc2   = Wbig  + 4 * HH;                    // 1*HH (512 x 512)
    _Float16* fc1h  = Wc2   + 1 * HH;                    // 6*HH
    _Float16* fc2h  = fc1h  + 6 * HH;                    // 2*HH
    float*    bco   = (float*)(fc2h + 2 * HH);           // 3*512
    float*    beff  = bco + 3 * 512;                     // 3*512 (g0|g1|g2)
    _Float16* hws   = wsH;                               // h' after chunk loop
    const size_t need = (size_t)((char*)(beff + 3 * 512) - (char*)d_ws);
    if (ws_size < need) return;

    const float* X[3] = { (const float*)d_in[0], (const float*)d_in[1], (const float*)d_in[2] };
    const int asrc[3] = { 1, 0, 2 };   // gate m's attention-source modality

    // ---- weight prep (all tiny) ----
    CvtJobs cj;
    for (int m = 0; m < 3; ++m) {
        cj.j[m]     = { (const float*)d_in[5 + 4 * m], Wouth + m * HH, 128, 512, 128, 512 };
        cj.j[3 + m] = { (const float*)d_in[15 + 2 * m] + 512, Wg2h + m * HH, 256, 512, 128, 512 };
    }
    cj.j[6]  = { (const float*)d_in[15], Wbig,                    256, 1024, 128, 512 };
    cj.j[7]  = { (const float*)d_in[17], Wbig + 512 * 1024 + 512, 256, 1024, 128, 512 };
    cj.j[8]  = { (const float*)d_in[19], Wc2,                     256, 512,  128, 512 };
    cj.j[9]  = { (const float*)d_in[21], fc1h, 384, 1536, 384, 1024 };
    cj.j[10] = { (const float*)d_in[25], fc2h, 256, 1024, 256, 512 };
    cvt_rows<<<dim3(1024, 11, 1), 256, 0, stream>>>(cj);

    TcvtArgs ta;
    for (int m = 0; m < 3; ++m) ta.src[m] = (const float*)d_in[3 + 4 * m] + 2 * HH;
    ta.dst = WvT;
    tcvt512<<<dim3(16, 16, 3), 256, 0, stream>>>(ta);

    MvArgs mv;   // bco_a = bo_a + Wout_a @ bv_a
    for (int m = 0; m < 3; ++m) {
        mv.W[m] = (const float*)d_in[5 + 4 * m];
        mv.x[m] = (const float*)d_in[4 + 4 * m] + 2 * HDIM;
        mv.b[m] = (const float*)d_in[6 + 4 * m];
    }
    mv.y = bco; mv.ldw = 512; mv.woff = 0;
    mv3<<<dim3(2, 3, 1), 256, 0, stream>>>(mv);

    GemmP p;
    p.bias = nullptr; p.coff = 0;
    p.zsA = p.zsW = p.zsC = 0;
    p.A1b = nullptr; p.Wb = nullptr; p.biasb = nullptr;
    p.Kb = 0; p.ldwb = 0; p.coffb = 0; p.ysplit = 1 << 30;

    // WcoT_a = WvT_a @ Wout_a^T  for a=0,1,2  (batched over z)
    p.A1 = WvT; p.ldA1 = 512;
    p.W = Wouth; p.ldw = 512;
    p.C = WcoT; p.ldc = 512;
    p.K = 512;
    p.zsA = (int)(HH * 2); p.zsW = (int)(HH * 2); p.zsC = (int)(HH * 2);
    gemm_k<0, 4, 0><<<dim3(4, 4, 3), 256, 0, stream>>>(p);

    // Wbig off-diagonal blocks, batched z=2:
    //   z0: Wbig[0:512, 512:1024]  = Wg2_0 @ Wco_1
    //   z1: Wbig[512:1024, 0:512]  = Wg2_1 @ Wco_0
    p.A1 = Wg2h; p.zsA = (int)(HH * 2);
    p.W = WcoT + HH; p.zsW = -(int)(HH * 2);
    p.C = Wbig + 512; p.ldc = 1024; p.zsC = (int)((512 * 1024 - 512) * 2);
    gemm_k<0, 4, 0><<<dim3(4, 4, 2), 256, 0, stream>>>(p);

    // Wc2 += Wg2_2 @ Wco_2  (RMW onto cvt'd Wg1_2)
    p.A1 = Wg2h + 2 * HH; p.zsA = 0;
    p.W = WcoT + 2 * HH; p.zsW = 0;
    p.C = Wc2; p.ldc = 512; p.zsC = 0;
    gemm_k<2, 4, 0><<<dim3(4, 4, 1), 256, 0, stream>>>(p);

    // beff_m = bg_m + Wg2_m @ bco_{asrc[m]}
    for (int m = 0; m < 3; ++m) {
        mv.W[m] = (const float*)d_in[15 + 2 * m];
        mv.x[m] = bco + asrc[m] * 512;
        mv.b[m] = (const float*)d_in[16 + 2 * m];
    }
    mv.y = beff; mv.ldw = 1024; mv.woff = 512;
    mv3<<<dim3(2, 3, 1), 256, 0, stream>>>(mv);

    // ---- main pipeline, 2 M-chunks so Xch/slotB stay L3-resident ----
    _Float16* hbuf = (_Float16*)d_out;   // h: M x 1024 fp16 inside d_out
    for (int c = 0; c < 2; ++c) {
        const size_t roff = (size_t)c * CH;

        // Xc = [X0 | X1 | X2] chunk, fp32 -> fp16 packed (ld 1536).
        // Standalone massively-parallel pass (1 float4/thread): r11 proved
        // folding this into a low-parallelism GEMM tail costs 3x its time.
        cvt_chunk3<<<dim3(CH, 1, 1), 384, 0, stream>>>(
            X[0] + roff * HDIM, X[1] + roff * HDIM, X[2] + roff * HDIM, Xch);

        // Merged gate dispatch (y-split, all blocks useful):
        //   y<8 : slotB[:,0:1024]    = Xc01 * sigmoid(Xc01 @ Wbig^T + beff)
        //   y>=8: slotB[:,1024:1536] = Xc2  * sigmoid(Xc2  @ Wc2^T  + beff[1024:])
        p.A1 = Xch; p.ldA1 = 1536;
        p.W = Wbig; p.ldw = 1024;
        p.bias = beff;
        p.C = slotB; p.ldc = 1536; p.coff = 0;
        p.K = 1024;
        p.A1b = Xch + 1024; p.Wb = Wc2; p.biasb = beff + 1024;
        p.Kb = 512; p.ldwb = 512; p.coffb = 1024; p.ysplit = 8;
        gemm_k<1, 4, 1><<<dim3(CH / BM, 12, 1), 256, 0, stream>>>(p);

        // h_chunk = allf_chunk @ fc1^T + fc1_b -> d_out (fp16)
        p.A1 = slotB; p.ldA1 = 1536;
        p.W = fc1h; p.ldw = 1536;
        p.bias = (const float*)d_in[22];
        p.C = hbuf + roff * 1024; p.ldc = 1024; p.coff = 0;
        p.K = 1536; p.ysplit = 1 << 30;
        gemm_k<0, 4, 0><<<dim3(CH / BM, 8, 1), 256, 0, stream>>>(p);
    }

    // LayerNorm + ReLU: h (d_out) -> h' (ws; slotB/Xch region is dead now)
    ln_relu<<<dim3(MROWS / 4, 1, 1), 256, 0, stream>>>(
        hbuf, hws, (const float*)d_in[23], (const float*)d_in[24]);

    // out = h' @ fc2^T + fc2_b (fp32) directly into d_out, single dispatch.
    // h' lives in ws, so d_out is write-only here: no read/write hazard.
    p.A1 = hws; p.ldA1 = 1024;
    p.W = fc2h; p.ldw = 1024;
    p.bias = (const float*)d_in[26];
    p.C = d_out; p.ldc = HDIM; p.coff = 0;
    p.K = 1024; p.ysplit = 1 << 30;
    gemm_k<3, 4, 0><<<dim3(MROWS / BM, HDIM / BN, 1), 256, 0, stream>>>(p);
}

// Round 13
// 454.018 us; speedup vs baseline: 1.1655x; 1.0058x over previous
//
#include <hip/hip_runtime.h>
#include <stdint.h>
#include <stddef.h>

#define MROWS 32768
#define HDIM  512
#define CH    16384
#define BM 128
#define BN 128
#define BK 64

typedef __attribute__((ext_vector_type(8))) _Float16 half8;
typedef __attribute__((ext_vector_type(4))) _Float16 half4v;
typedef __attribute__((ext_vector_type(4))) float    f32x4;

// global -> LDS direct (16B/lane). LDS dest = wave-uniform base + lane*16.
static __device__ __forceinline__ void gld_lds16(const void* g, void* l) {
    __builtin_amdgcn_global_load_lds(
        (__attribute__((address_space(1))) void*)(uintptr_t)g,
        (__attribute__((address_space(3))) void*)(uint32_t)(uintptr_t)l,
        16, 0, 0);
}

// ---------------- fp32 -> fp16 row-structured conversion (weights) ------------
struct CvtJob  { const float* src; _Float16* dst; int srcld4, dstld, rowlen4, rows; };
struct CvtJobs { CvtJob j[11]; };

__global__ __launch_bounds__(256)
void cvt_rows(CvtJobs J) {
    const CvtJob jb = J.j[blockIdx.y];
    const int row = blockIdx.x;
    if (row >= jb.rows) return;
    const float4* __restrict__ s = (const float4*)jb.src + (size_t)row * jb.srcld4;
    _Float16* __restrict__ d = jb.dst + (size_t)row * jb.dstld;
    for (int c = threadIdx.x; c < jb.rowlen4; c += 256) {
        const float4 v = s[c];
        half4v o = { (_Float16)v.x, (_Float16)v.y, (_Float16)v.z, (_Float16)v.w };
        *(half4v*)(d + c * 4) = o;
    }
}

// ---------------- fp32 X chunk -> packed fp16 strip [X0|X1|X2] (ld 1536) ------
__global__ __launch_bounds__(384)
void cvt_chunk3(const float* __restrict__ x0, const float* __restrict__ x1,
                const float* __restrict__ x2, _Float16* __restrict__ dst) {
    const int row = blockIdx.x;
    const int mod = threadIdx.x >> 7;      // 0..2 (wave-uniform)
    const int c   = threadIdx.x & 127;     // float4 index within row
    const float* s = (mod == 0) ? x0 : (mod == 1) ? x1 : x2;
    const float4 v = ((const float4*)(s + (size_t)row * 512))[c];
    half4v o = { (_Float16)v.x, (_Float16)v.y, (_Float16)v.z, (_Float16)v.w };
    *(half4v*)(dst + (size_t)row * 1536 + mod * 512 + c * 4) = o;
}

// ---------------- fp32 -> fp16 transpose (512x512): dst[k][i] = src[i][k] -----
struct TcvtArgs { const float* src[3]; _Float16* dst; };
__global__ __launch_bounds__(256)
void tcvt512(TcvtArgs a) {
    __shared__ float t[32][33];
    const int m = blockIdx.z;
    const float* __restrict__ src = a.src[m];
    _Float16* __restrict__ dst = a.dst + (size_t)m * HDIM * HDIM;
    const int bx = blockIdx.x * 32, by = blockIdx.y * 32;
    const int tx = threadIdx.x & 31, ty = threadIdx.x >> 5;  // ty 0..7
    #pragma unroll
    for (int q = 0; q < 4; ++q)
        t[ty + q * 8][tx] = src[(size_t)(by + ty + q * 8) * 512 + bx + tx];
    __syncthreads();
    #pragma unroll
    for (int q = 0; q < 4; ++q)
        dst[(size_t)(bx + ty + q * 8) * 512 + by + tx] = (_Float16)t[tx][ty + q * 8];
}

// ---------------- small matvec ------------------------------------------------
struct MvArgs { const float* W[3]; const float* x[3]; const float* b[3]; float* y; int ldw, woff; };
__global__ __launch_bounds__(256)
void mv3(MvArgs a) {
    const int m = blockIdx.y;
    const int i = blockIdx.x * 256 + threadIdx.x;
    const float* __restrict__ W = a.W[m] + (size_t)i * a.ldw + a.woff;
    const float* __restrict__ x = a.x[m];
    float s = a.b[m][i];
    for (int j = 0; j < 512; ++j) s += W[j] * x[j];
    a.y[m * 512 + i] = s;
}

// ---------------- 1-phase GEMM (prep / gate2 / fc2), proven r9-r12 ------------
// EPI 0: fp16 store acc+bias.  1: fp16 store Xmul*sigmoid(acc+bias) (Xmul = A
// cols n0.., reloaded from global, L3-hit).  2: fp16 RMW.  3: fp32 store.
struct GemmP {
    const void* A1;
    const _Float16* W; const float* bias; void* C;
    int K, ldA1, ldw, ldc, coff;
    int zsA, zsW, zsC;
};

template<int EPI, int OCC>
__global__ __launch_bounds__(256, OCC)
void gemm_k(GemmP p) {
    __shared__ __align__(16) unsigned char smem[32768];
    _Float16* Asm = (_Float16*)smem;
    _Float16* Bsm = (_Float16*)(smem + 16384);

    const int tid  = threadIdx.x;
    const int wid  = tid >> 6;
    const int lane = tid & 63;
    const int m0 = blockIdx.x * BM;
    const int n0 = blockIdx.y * BN;
    const ptrdiff_t zz = (ptrdiff_t)blockIdx.z;
    const _Float16* __restrict__ A1h = (const _Float16*)((const char*)p.A1 + zz * p.zsA);
    const _Float16* __restrict__ Wp  = (const _Float16*)((const char*)p.W + zz * p.zsW);
    char* Cz = (char*)p.C + zz * p.zsC;

    const int wr = (wid >> 1) * 64;
    const int wc = (wid & 1) * 64;
    const int l15 = lane & 15;
    const int lhi = lane >> 4;

    f32x4 acc[4][4] = {};

    for (int kt = 0; kt < p.K; kt += BK) {
        #pragma unroll
        for (int i = 0; i < 4; ++i) {
            const int seg = wid * 256 + i * 64 + lane;
            const int row = seg >> 3;
            const int ke  = (seg & 7) * 8;
            gld_lds16(Wp  + (size_t)(n0 + row) * p.ldw  + kt + ke, &Bsm[seg * 8]);
            gld_lds16(A1h + (size_t)(m0 + row) * p.ldA1 + kt + ke, &Asm[seg * 8]);
        }
        __syncthreads();
        #pragma unroll
        for (int kk = 0; kk < BK; kk += 32) {
            half8 fa[4], fb[4];
            #pragma unroll
            for (int i = 0; i < 4; ++i) {
                fa[i] = *(const half8*)&Asm[(wr + i * 16 + l15) * BK + kk + lhi * 8];
                fb[i] = *(const half8*)&Bsm[(wc + i * 16 + l15) * BK + kk + lhi * 8];
            }
            #pragma unroll
            for (int i = 0; i < 4; ++i)
                #pragma unroll
                for (int j = 0; j < 4; ++j)
                    acc[i][j] = __builtin_amdgcn_mfma_f32_16x16x32_f16(fa[i], fb[j], acc[i][j], 0, 0, 0);
        }
        __syncthreads();
    }

    if (EPI == 3) {
        float* Cf = (float*)smem;
        float* __restrict__ C = (float*)Cz;
        #pragma unroll
        for (int h = 0; h < 2; ++h) {
            if ((wr >> 6) == h) {
                #pragma unroll
                for (int j = 0; j < 4; ++j) {
                    const int col = wc + j * 16 + l15;
                    const float bia = p.bias ? p.bias[n0 + col] : 0.f;
                    #pragma unroll
                    for (int i = 0; i < 4; ++i)
                        #pragma unroll
                        for (int r = 0; r < 4; ++r)
                            Cf[(i * 16 + lhi * 4 + r) * 128 + col] = acc[i][j][r] + bia;
                }
            }
            __syncthreads();
            #pragma unroll
            for (int pph = 0; pph < 8; ++pph) {
                const int seg = pph * 256 + tid;
                const int row = seg >> 5, cs = seg & 31;
                const float4 v = *(const float4*)&Cf[row * 128 + cs * 4];
                *(float4*)&C[(size_t)(m0 + h * 64 + row) * p.ldc + n0 + cs * 4] = v;
            }
            __syncthreads();
        }
    } else {
        _Float16* Ct = (_Float16*)smem;
        #pragma unroll
        for (int j = 0; j < 4; ++j) {
            const int col = wc + j * 16 + l15;
            const float bia = (EPI == 2) ? 0.f : (p.bias ? p.bias[n0 + col] : 0.f);
            #pragma unroll
            for (int i = 0; i < 4; ++i)
                #pragma unroll
                for (int r = 0; r < 4; ++r) {
                    float v = acc[i][j][r] + bia;
                    if (EPI == 1) v = 1.f / (1.f + __expf(-v));
                    Ct[(wr + i * 16 + lhi * 4 + r) * 128 + col] = (_Float16)v;
                }
        }
        __syncthreads();
        _Float16* __restrict__ C = (_Float16*)Cz;
        #pragma unroll
        for (int pph = 0; pph < 8; ++pph) {
            const int seg = pph * 256 + tid;
            const int row = seg >> 4, cs = seg & 15;
            half8 hv = *(const half8*)&Ct[row * 128 + cs * 8];
            const size_t cidx = (size_t)(m0 + row) * p.ldc + p.coff + n0 + cs * 8;
            if (EPI == 1) {
                const half8 xv = *(const half8*)(A1h + (size_t)(m0 + row) * p.ldA1
                                                 + n0 + cs * 8);
                hv = hv * xv;
            }
            if (EPI == 2) { const half8 old = *(const half8*)&C[cidx]; hv = hv + old; }
            *(half8*)&C[cidx] = hv;
        }
    }
}

// ---------------- 8-phase 256x256 GEMM (T2+T3+T4+T5), gate01 & fc1 -----------
// 512 thr = 8 waves (2M x 4N); per-wave out 128x64; BK=64; LDS 128KB 2-dbuf.
// Per K-tile: 4 phases {ds_read frags; (ph0: issue ALL next-tile staging);
// s_barrier; lgkmcnt(0); 16 MFMA; (ph3: vmcnt(0)); s_barrier}.
// Race-freedom: staging into buf[q^1] issues only after all reads of buf[q^1]
// completed (phase barriers); reads of tile t+1 gated by ph3 vmcnt(0)+barrier.
// T2 swizzle: col16 ^= (row&7), applied on pre-swizzled GLOBAL source (m173)
// and identically on ds_read addresses -> 16-way bank conflict becomes 2-way.
struct Gemm8P {
    const _Float16* A; const _Float16* W; const float* bias; _Float16* C;
    int K, ldA, ldW, ldc, coff;
};

template<int EPI>
__global__ __launch_bounds__(512, 1)
void gemm8(Gemm8P p) {
    __shared__ __align__(16) unsigned char lds[131072];
    char* LA = (char*)lds;             // A: [2 buf][256 rows][8 x 16B]
    char* LB = (char*)lds + 65536;     // B: same

    const int tid  = threadIdx.x;
    const int wid  = tid >> 6;
    const int lane = tid & 63;
    const int wm = wid >> 2;           // 0..1
    const int wn = wid & 3;            // 0..3
    const int l15 = lane & 15;
    const int lhi = lane >> 4;
    const int m0 = blockIdx.x * 256;
    const int n0 = blockIdx.y * 256;
    const _Float16* __restrict__ A = p.A;
    const _Float16* __restrict__ W = p.W;
    const int ldA = p.ldA, ldW = p.ldW;
    const int nT = p.K >> 6;

    f32x4 acc[8][4] = {};

    // stage tile t (64 K-cols) into buffer parity q = t&1, pre-swizzled source
    auto stage = [&](int t) {
        const int q = t & 1;
        const int kt = t * 64;
        #pragma unroll
        for (int k = 0; k < 4; ++k) {
            const int u = tid + k * 512;              // 16B unit 0..2047
            const int row = u >> 3;
            const int sc = (u & 7) ^ (row & 7);       // inverse swizzle on src
            gld_lds16(A + (size_t)(m0 + row) * ldA + kt + sc * 8,
                      LA + ((size_t)q * 2048 + u) * 16);
        }
        #pragma unroll
        for (int k = 0; k < 4; ++k) {
            const int u = tid + k * 512;
            const int row = u >> 3;
            const int sc = (u & 7) ^ (row & 7);
            gld_lds16(W + (size_t)(n0 + row) * ldW + kt + sc * 8,
                      LB + ((size_t)q * 2048 + u) * 16);
        }
    };

    stage(0);
    asm volatile("s_waitcnt vmcnt(0)" ::: "memory");
    __builtin_amdgcn_s_barrier();
    asm volatile("" ::: "memory");

    for (int t = 0; t < nT; ++t) {
        const size_t aq = (size_t)(t & 1) * 2048 * 16;
        half8 fb[4][2];
        #pragma unroll
        for (int ph = 0; ph < 4; ++ph) {
            half8 fa[2][2];
            if (ph == 0) {
                #pragma unroll
                for (int nf = 0; nf < 4; ++nf)
                    #pragma unroll
                    for (int kh = 0; kh < 2; ++kh) {
                        const int row = wn * 64 + nf * 16 + l15;
                        const int c16 = (kh * 4 + lhi) ^ (row & 7);   // swizzled read
                        fb[nf][kh] = *(const half8*)(LB + aq + ((size_t)row * 8 + c16) * 16);
                    }
            }
            #pragma unroll
            for (int mi = 0; mi < 2; ++mi)
                #pragma unroll
                for (int kh = 0; kh < 2; ++kh) {
                    const int row = wm * 128 + (ph * 2 + mi) * 16 + l15;
                    const int c16 = (kh * 4 + lhi) ^ (row & 7);
                    fa[mi][kh] = *(const half8*)(LA + aq + ((size_t)row * 8 + c16) * 16);
                }
            if (ph == 0 && t + 1 < nT) stage(t + 1);
            asm volatile("" ::: "memory");
            __builtin_amdgcn_s_barrier();
            asm volatile("s_waitcnt lgkmcnt(0)" ::: "memory");
            __builtin_amdgcn_sched_barrier(0);
            __builtin_amdgcn_s_setprio(1);
            #pragma unroll
            for (int mi = 0; mi < 2; ++mi)
                #pragma unroll
                for (int nf = 0; nf < 4; ++nf)
                    #pragma unroll
                    for (int kh = 0; kh < 2; ++kh)
                        acc[ph * 2 + mi][nf] = __builtin_amdgcn_mfma_f32_16x16x32_f16(
                            fa[mi][kh], fb[nf][kh], acc[ph * 2 + mi][nf], 0, 0, 0);
            __builtin_amdgcn_s_setprio(0);
            if (ph == 3) asm volatile("s_waitcnt vmcnt(0)" ::: "memory");
            asm volatile("" ::: "memory");
            __builtin_amdgcn_s_barrier();
            asm volatile("" ::: "memory");
        }
    }

    // epilogue: fragments -> LDS (256x256 fp16 = 128KB, buffers dead) -> stores
    _Float16* Ct = (_Float16*)lds;
    #pragma unroll
    for (int mf = 0; mf < 8; ++mf)
        #pragma unroll
        for (int nf = 0; nf < 4; ++nf) {
            const int col = wn * 64 + nf * 16 + l15;
            const float bia = p.bias[n0 + col];
            #pragma unroll
            for (int r = 0; r < 4; ++r) {
                float v = acc[mf][nf][r] + bia;
                if (EPI == 1) v = 1.f / (1.f + __expf(-v));   // sigma
                Ct[(wm * 128 + mf * 16 + lhi * 4 + r) * 256 + col] = (_Float16)v;
            }
        }
    __syncthreads();
    #pragma unroll
    for (int it = 0; it < 16; ++it) {
        const int u = it * 512 + tid;          // 8192 x 16B units
        const int row = u >> 5, cs = u & 31;
        half8 hv = *(const half8*)&Ct[row * 256 + cs * 8];
        if (EPI == 1) {
            const half8 xv = *(const half8*)(A + (size_t)(m0 + row) * ldA + n0 + cs * 8);
            hv = hv * xv;                       // x * sigmoid
        }
        *(half8*)&p.C[(size_t)(m0 + row) * p.ldc + p.coff + n0 + cs * 8] = hv;
    }
}

// ---------------- LayerNorm(1024) + ReLU: d_out(h fp16) -> ws(h' fp16) --------
__global__ __launch_bounds__(256)
void ln_relu(const _Float16* __restrict__ hin, _Float16* __restrict__ hout,
             const float* __restrict__ gamma, const float* __restrict__ beta) {
    const int row  = blockIdx.x * 4 + (threadIdx.x >> 6);
    const int lane = threadIdx.x & 63;
    const _Float16* hr = hin + (size_t)row * 1024;
    _Float16* ho = hout + (size_t)row * 1024;
    const half8 v0 = *(const half8*)(hr + lane * 8);
    const half8 v1 = *(const half8*)(hr + 512 + lane * 8);
    float f0[8], f1[8];
    float s = 0.f, s2 = 0.f;
    #pragma unroll
    for (int j = 0; j < 8; ++j) {
        f0[j] = (float)v0[j]; s += f0[j]; s2 += f0[j] * f0[j];
        f1[j] = (float)v1[j]; s += f1[j]; s2 += f1[j] * f1[j];
    }
    #pragma unroll
    for (int off = 32; off > 0; off >>= 1) {
        s  += __shfl_xor(s,  off, 64);
        s2 += __shfl_xor(s2, off, 64);
    }
    const float mean = s * (1.f / 1024.f);
    const float var  = s2 * (1.f / 1024.f) - mean * mean;
    const float rstd = rsqrtf(var + 1e-5f);
    half8 o0, o1;
    #pragma unroll
    for (int j = 0; j < 8; ++j) {
        const int i0 = lane * 8 + j, i1 = 512 + lane * 8 + j;
        const float av = (f0[j] - mean) * rstd * gamma[i0] + beta[i0];
        const float bv = (f1[j] - mean) * rstd * gamma[i1] + beta[i1];
        o0[j] = (_Float16)(av > 0.f ? av : 0.f);
        o1[j] = (_Float16)(bv > 0.f ? bv : 0.f);
    }
    *(half8*)(ho + lane * 8) = o0;
    *(half8*)(ho + 512 + lane * 8) = o1;
}

// -----------------------------------------------------------------------------
extern "C" void kernel_launch(void* const* d_in, const int* in_sizes, int n_in,
                              void* d_out, int out_size, void* d_ws, size_t ws_size,
                              hipStream_t stream)
{
    (void)in_sizes; (void)n_in; (void)out_size;
    const size_t HH = (size_t)HDIM * HDIM;              // 262,144

    // ws layout (~113.8 MB; r9-r12 proved ws >= this)
    _Float16* wsH   = (_Float16*)d_ws;
    _Float16* slotB = wsH;                               // CH*1536
    _Float16* Xch   = slotB + (size_t)CH * 1536;         // CH*1536
    _Float16* Wouth = Xch   + (size_t)CH * 1536;         // 3*HH
    _Float16* Wg2h  = Wouth + 3 * HH;                    // 3*HH
    _Float16* WvT   = Wg2h  + 3 * HH;                    // 3*HH
    _Float16* WcoT  = WvT   + 3 * HH;                    // 3*HH
    _Float16* Wbig  = WcoT  + 3 * HH;                    // 4*HH (1024 x 1024)
    _Float16* Wc2   = Wbig  + 4 * HH;                    // 1*HH (512 x 512)
    _Float16* fc1h  = Wc2   + 1 * HH;                    // 6*HH
    _Float16* fc2h  = fc1h  + 6 * HH;                    // 2*HH
    float*    bco   = (float*)(fc2h + 2 * HH);           // 3*512
    float*    beff  = bco + 3 * 512;                     // 3*512
    _Float16* hws   = wsH;                               // h' after chunk loop
    const size_t need = (size_t)((char*)(beff + 3 * 512) - (char*)d_ws);
    if (ws_size < need) return;

    const float* X[3] = { (const float*)d_in[0], (const float*)d_in[1], (const float*)d_in[2] };
    const int asrc[3] = { 1, 0, 2 };

    // ---- weight prep (all tiny) ----
    CvtJobs cj;
    for (int m = 0; m < 3; ++m) {
        cj.j[m]     = { (const float*)d_in[5 + 4 * m], Wouth + m * HH, 128, 512, 128, 512 };
        cj.j[3 + m] = { (const float*)d_in[15 + 2 * m] + 512, Wg2h + m * HH, 256, 512, 128, 512 };
    }
    cj.j[6]  = { (const float*)d_in[15], Wbig,                    256, 1024, 128, 512 };
    cj.j[7]  = { (const float*)d_in[17], Wbig + 512 * 1024 + 512, 256, 1024, 128, 512 };
    cj.j[8]  = { (const float*)d_in[19], Wc2,                     256, 512,  128, 512 };
    cj.j[9]  = { (const float*)d_in[21], fc1h, 384, 1536, 384, 1024 };
    cj.j[10] = { (const float*)d_in[25], fc2h, 256, 1024, 256, 512 };
    cvt_rows<<<dim3(1024, 11, 1), 256, 0, stream>>>(cj);

    TcvtArgs ta;
    for (int m = 0; m < 3; ++m) ta.src[m] = (const float*)d_in[3 + 4 * m] + 2 * HH;
    ta.dst = WvT;
    tcvt512<<<dim3(16, 16, 3), 256, 0, stream>>>(ta);

    MvArgs mv;
    for (int m = 0; m < 3; ++m) {
        mv.W[m] = (const float*)d_in[5 + 4 * m];
        mv.x[m] = (const float*)d_in[4 + 4 * m] + 2 * HDIM;
        mv.b[m] = (const float*)d_in[6 + 4 * m];
    }
    mv.y = bco; mv.ldw = 512; mv.woff = 0;
    mv3<<<dim3(2, 3, 1), 256, 0, stream>>>(mv);

    GemmP p;
    p.bias = nullptr; p.coff = 0;
    p.zsA = p.zsW = p.zsC = 0;

    // WcoT_a = WvT_a @ Wout_a^T  (batched over z)
    p.A1 = WvT; p.ldA1 = 512;
    p.W = Wouth; p.ldw = 512;
    p.C = WcoT; p.ldc = 512;
    p.K = 512;
    p.zsA = (int)(HH * 2); p.zsW = (int)(HH * 2); p.zsC = (int)(HH * 2);
    gemm_k<0, 4><<<dim3(4, 4, 3), 256, 0, stream>>>(p);

    // Wbig off-diagonal blocks (z=2)
    p.A1 = Wg2h; p.zsA = (int)(HH * 2);
    p.W = WcoT + HH; p.zsW = -(int)(HH * 2);
    p.C = Wbig + 512; p.ldc = 1024; p.zsC = (int)((512 * 1024 - 512) * 2);
    gemm_k<0, 4><<<dim3(4, 4, 2), 256, 0, stream>>>(p);

    // Wc2 += Wg2_2 @ Wco_2
    p.A1 = Wg2h + 2 * HH; p.zsA = 0;
    p.W = WcoT + 2 * HH; p.zsW = 0;
    p.C = Wc2; p.ldc = 512; p.zsC = 0;
    gemm_k<2, 4><<<dim3(4, 4, 1), 256, 0, stream>>>(p);

    // beff
    for (int m = 0; m < 3; ++m) {
        mv.W[m] = (const float*)d_in[15 + 2 * m];
        mv.x[m] = bco + asrc[m] * 512;
        mv.b[m] = (const float*)d_in[16 + 2 * m];
    }
    mv.y = beff; mv.ldw = 1024; mv.woff = 512;
    mv3<<<dim3(2, 3, 1), 256, 0, stream>>>(mv);

    // ---- main pipeline, 2 M-chunks ----
    _Float16* hbuf = (_Float16*)d_out;
    Gemm8P g8;
    for (int c = 0; c < 2; ++c) {
        const size_t roff = (size_t)c * CH;

        cvt_chunk3<<<dim3(CH, 1, 1), 384, 0, stream>>>(
            X[0] + roff * HDIM, X[1] + roff * HDIM, X[2] + roff * HDIM, Xch);

        // gate01 (8-phase 256^2): slotB[:,0:1024] = Xc01 * sigma(Xc01 @ Wbig^T + beff)
        g8.A = Xch; g8.ldA = 1536;
        g8.W = Wbig; g8.ldW = 1024;
        g8.bias = beff;
        g8.C = slotB; g8.ldc = 1536; g8.coff = 0;
        g8.K = 1024;
        gemm8<1><<<dim3(CH / 256, 4, 1), 512, 0, stream>>>(g8);

        // gate2 (1-phase, proven): slotB[:,1024:1536]
        p.A1 = Xch + 1024; p.ldA1 = 1536;
        p.W = Wc2; p.ldw = 512;
        p.bias = beff + 1024;
        p.C = slotB; p.ldc = 1536; p.coff = 1024;
        p.K = 512; p.zsA = p.zsW = p.zsC = 0;
        gemm_k<1, 4><<<dim3(CH / BM, 4, 1), 256, 0, stream>>>(p);

        // fc1 (8-phase 256^2): h_chunk = allf @ fc1^T + fc1_b -> d_out fp16
        g8.A = slotB; g8.ldA = 1536;
        g8.W = fc1h; g8.ldW = 1536;
        g8.bias = (const float*)d_in[22];
        g8.C = hbuf + roff * 1024; g8.ldc = 1024; g8.coff = 0;
        g8.K = 1536;
        gemm8<0><<<dim3(CH / 256, 4, 1), 512, 0, stream>>>(g8);
    }

    // LayerNorm + ReLU: h (d_out) -> h' (ws)
    ln_relu<<<dim3(MROWS / 4, 1, 1), 256, 0, stream>>>(
        hbuf, hws, (const float*)d_in[23], (const float*)d_in[24]);

    // fc2 (1-phase EPI3): out = h' @ fc2^T + fc2_b -> d_out fp32
    p.A1 = hws; p.ldA1 = 1024;
    p.W = fc2h; p.ldw = 1024;
    p.bias = (const float*)d_in[26];
    p.C = d_out; p.ldc = HDIM; p.coff = 0;
    p.K = 1024; p.zsA = p.zsW = p.zsC = 0;
    gemm_k<3, 4><<<dim3(MROWS / BM, HDIM / BN, 1), 256, 0, stream>>>(p);
}